// Round 2
// baseline (13797.411 us; speedup 1.0000x reference)
//
#include <hip/hip_runtime.h>
#include <cmath>

// Problem constants
#define BB 64
#define LL 96
#define HH 1024
#define MM 512
#define LH 98304            // L*H
#define ATT0 6291456        // B*L*H  (start of attn outputs in d_out)

__device__ __forceinline__ float sigmoidf_(float x) { return 1.0f / (1.0f + expf(-x)); }

// ---------------------------------------------------------------------------
// Split-K GEMM:  P[s][b][n] = sum_{k in split s} A(b,k) * W(n,k)
// A is the virtual concat of A0 [64 x K0] (row stride lda0) and A1 (stride lda1).
// W is row-major [N x K]. No bias/activation here (folded into reduce kernels).
// block = 256 threads, tile = 64 rows x 64 cols, K-chunk staged in LDS 16 at a time.
// ---------------------------------------------------------------------------
__global__ __launch_bounds__(256) void gemm_splitk(
    const float* __restrict__ A0, int lda0, int K0,
    const float* __restrict__ A1, int lda1,
    const float* __restrict__ W, int K,
    float* __restrict__ P, int N, int kchunk)
{
    __shared__ __align__(16) float As[16][64];
    __shared__ __align__(16) float Ws[16][64];
    const int t    = threadIdx.x;
    const int n0   = blockIdx.x * 64;
    const int kbeg = blockIdx.y * kchunk;
    const int kend = kbeg + kchunk;
    const int r    = t >> 2;        // 0..63 (staging row)
    const int cq   = (t & 3) << 2;  // 0,4,8,12 (staging col)
    const int tr   = t >> 4;        // 0..15
    const int tc   = t & 15;        // 0..15

    float acc[4][4] = {{0.f}};

    auto loadA = [&](int k) -> float4 {
        const float* p;
        if (k < K0) p = A0 + (size_t)r * lda0 + k;
        else        p = A1 + (size_t)r * lda1 + (k - K0);
        return *(const float4*)(p + cq);
    };
    auto loadW = [&](int k) -> float4 {
        return *(const float4*)(W + (size_t)(n0 + r) * K + k + cq);
    };

    float4 av = loadA(kbeg);
    float4 wv = loadW(kbeg);

    for (int k0 = kbeg; k0 < kend; k0 += 16) {
        __syncthreads();
        As[cq + 0][r] = av.x; As[cq + 1][r] = av.y; As[cq + 2][r] = av.z; As[cq + 3][r] = av.w;
        Ws[cq + 0][r] = wv.x; Ws[cq + 1][r] = wv.y; Ws[cq + 2][r] = wv.z; Ws[cq + 3][r] = wv.w;
        __syncthreads();
        if (k0 + 16 < kend) { av = loadA(k0 + 16); wv = loadW(k0 + 16); }
        #pragma unroll
        for (int kk = 0; kk < 16; ++kk) {
            float4 a4 = *(const float4*)&As[kk][tr << 2];
            float4 w4 = *(const float4*)&Ws[kk][tc << 2];
            float aa[4] = {a4.x, a4.y, a4.z, a4.w};
            float ww[4] = {w4.x, w4.y, w4.z, w4.w};
            #pragma unroll
            for (int i = 0; i < 4; ++i)
                #pragma unroll
                for (int j = 0; j < 4; ++j)
                    acc[i][j] += aa[i] * ww[j];
        }
    }

    float* dst = P + (size_t)(blockIdx.y * 64) * N + n0;
    #pragma unroll
    for (int i = 0; i < 4; ++i) {
        float4 st = make_float4(acc[i][0], acc[i][1], acc[i][2], acc[i][3]);
        *(float4*)(dst + (size_t)((tr << 2) + i) * N + (tc << 2)) = st;
    }
}

// ---------------------------------------------------------------------------
// Softmax over M=512 (summing split-K partials + bias), write normalized attn
// to d_out, then applied[b,h] = sum_m aw[m] * enc[b,m,h] for this block's
// h-slice. grid = (64 b, 4 h-chunks), 256 threads.
// ---------------------------------------------------------------------------
__global__ __launch_bounds__(256) void softmax_einsum(
    const float* __restrict__ zp,    // [8][64][512] partials
    const float* __restrict__ ba,    // [512]
    const float* __restrict__ enc,   // [64][512][1024]
    float* __restrict__ applied,     // [64][1024]
    float* __restrict__ attn_out,    // d_out + ATT0 + step*512; index b*L*M + m
    int nsplit)
{
    __shared__ float aw[512];
    __shared__ float red[4];
    const int b  = blockIdx.x;
    const int hc = blockIdx.y;
    const int t  = threadIdx.x;

    float z0 = ba[t], z1 = ba[t + 256];
    for (int s = 0; s < nsplit; ++s) {
        const float* zr = zp + ((size_t)(s * 64 + b) << 9);
        z0 += zr[t];
        z1 += zr[t + 256];
    }
    float mx = fmaxf(z0, z1);
    #pragma unroll
    for (int off = 32; off >= 1; off >>= 1) mx = fmaxf(mx, __shfl_xor(mx, off));
    if ((t & 63) == 0) red[t >> 6] = mx;
    __syncthreads();
    mx = fmaxf(fmaxf(red[0], red[1]), fmaxf(red[2], red[3]));

    float e0 = expf(z0 - mx), e1 = expf(z1 - mx);
    aw[t] = e0; aw[t + 256] = e1;
    float ss = e0 + e1;
    #pragma unroll
    for (int off = 32; off >= 1; off >>= 1) ss += __shfl_xor(ss, off);
    __syncthreads();                 // red reads done; aw writes done
    if ((t & 63) == 0) red[t >> 6] = ss;
    __syncthreads();
    const float rinv = 1.0f / (red[0] + red[1] + red[2] + red[3]);

    if (hc == 0) {
        attn_out[(size_t)b * (LL * MM) + t]       = e0 * rinv;
        attn_out[(size_t)b * (LL * MM) + t + 256] = e1 * rinv;
    }

    // phase 2: weighted sum over encode_outputs
    const int h = (hc << 8) + t;
    const float* eb = enc + ((size_t)b << 19) + h;
    float acc = 0.f;
    #pragma unroll 8
    for (int mm = 0; mm < 512; ++mm) acc += aw[mm] * eb[(size_t)mm << 10];
    applied[(b << 10) + h] = acc * rinv;
}

// ---------------------------------------------------------------------------
// out[b, n] = relu(sum_s P[s][b][n] + bias[n]); 65536 elements, grid 256x256
// ---------------------------------------------------------------------------
__global__ __launch_bounds__(256) void reduce_act(
    const float* __restrict__ P, int nsplit, const float* __restrict__ bias,
    float* __restrict__ outp, int ostride)
{
    const int idx = blockIdx.x * 256 + threadIdx.x;
    const int b = idx >> 10, n = idx & 1023;
    float v = bias[n];
    for (int s = 0; s < nsplit; ++s) v += P[((size_t)(s * 64 + b) << 10) + n];
    outp[(size_t)b * ostride + n] = fmaxf(v, 0.f);
}

// ---------------------------------------------------------------------------
// LSTM pointwise from gate partials gp[s][b][4096] (+ summed bias),
// c_prev -> h_out, c_out. 65536 elements, grid 256x256.
// ---------------------------------------------------------------------------
__global__ __launch_bounds__(256) void reduce_lstm(
    const float* __restrict__ gp, int nsplit, const float* __restrict__ bsum,
    const float* __restrict__ c_prev, float* __restrict__ h_out, float* __restrict__ c_out)
{
    const int idx = blockIdx.x * 256 + threadIdx.x;
    const int b = idx >> 10, j = idx & 1023;
    float gi = bsum[j], gf = bsum[1024 + j], gg = bsum[2048 + j], go = bsum[3072 + j];
    for (int s = 0; s < nsplit; ++s) {
        const float* g = gp + ((size_t)(s * 64 + b) << 12);
        gi += g[j]; gf += g[1024 + j]; gg += g[2048 + j]; go += g[3072 + j];
    }
    const float c  = c_prev[idx];
    const float cn = sigmoidf_(gf) * c + sigmoidf_(gi) * tanhf(gg);
    c_out[idx] = cn;
    h_out[idx] = sigmoidf_(go) * tanhf(cn);
}

// ---------------------------------------------------------------------------
// Precompute kernels (run once per launch)
// ---------------------------------------------------------------------------
__global__ void pack_w1(const float* __restrict__ Wih, const float* __restrict__ Whh,
                        float* __restrict__ Wcat)
{
    // Wcat[4096][2048] = [Wih | Whh]
    const int total = 4096 * 2048;
    for (int i = blockIdx.x * blockDim.x + threadIdx.x; i < total; i += blockDim.x * gridDim.x) {
        const int n = i >> 11, k = i & 2047;
        Wcat[i] = (k < 1024) ? Wih[(n << 10) + k] : Whh[(n << 10) + k - 1024];
    }
}

__global__ void add_vec(const float* __restrict__ a, const float* __restrict__ b,
                        float* __restrict__ o, int n)
{
    for (int i = blockIdx.x * blockDim.x + threadIdx.x; i < n; i += blockDim.x * gridDim.x)
        o[i] = a[i] + b[i];
}

// ---------------------------------------------------------------------------
extern "C" void kernel_launch(void* const* d_in, const int* in_sizes, int n_in,
                              void* d_out, int out_size, void* d_ws, size_t ws_size,
                              hipStream_t stream)
{
    (void)in_sizes; (void)n_in; (void)out_size; (void)ws_size;

    const float* decode_input = (const float*)d_in[0];
    const float* h0   = (const float*)d_in[1];
    const float* c0   = (const float*)d_in[2];
    const float* enc  = (const float*)d_in[3];
    const float* Wa   = (const float*)d_in[4];
    const float* ba   = (const float*)d_in[5];
    const float* Wc   = (const float*)d_in[6];
    const float* bc   = (const float*)d_in[7];
    const float* Wo   = (const float*)d_in[8];
    const float* bo   = (const float*)d_in[9];
    const float* W1ih = (const float*)d_in[10];
    const float* W1hh = (const float*)d_in[11];
    const float* b1ih = (const float*)d_in[12];
    const float* b1hh = (const float*)d_in[13];
    const float* W2ih = (const float*)d_in[14];
    const float* W2hh = (const float*)d_in[15];
    const float* b2ih = (const float*)d_in[16];
    const float* b2hh = (const float*)d_in[17];
    const float* W3ih = (const float*)d_in[18];
    const float* W3hh = (const float*)d_in[19];
    const float* b3ih = (const float*)d_in[20];
    const float* b3hh = (const float*)d_in[21];

    float* out = (float*)d_out;
    float* ws  = (float*)d_ws;

    // workspace layout (floats)
    float* w1cat   = ws;                      // 4096*2048 = 8388608
    float* w2s     = w1cat + 8388608;         // 4096*1024 = 4194304
    float* w3s     = w2s   + 4194304;         // 4194304
    float* b1s     = w3s   + 4194304;         // 4096
    float* b2s     = b1s   + 4096;            // 4096
    float* b3s     = b2s   + 4096;            // 4096
    float* zp      = b3s   + 4096;            // 8*64*512 = 262144 (also reused for O partials)
    float* cpart   = zp    + 262144;          // 8*64*1024 = 524288
    float* gp      = cpart + 524288;          // 8*64*4096 = 2097152
    float* applied = gp    + 2097152;         // 65536
    float* comb    = applied + 65536;         // 65536
    float* h1      = comb  + 65536;
    float* h2      = h1    + 65536;
    float* h3      = h2    + 65536;
    float* c1      = h3    + 65536;
    float* c2      = c1    + 65536;
    float* c3      = c2    + 65536;

    // ---- precompute fused weights/biases ----
    pack_w1<<<2048, 256, 0, stream>>>(W1ih, W1hh, w1cat);
    add_vec<<<2048, 256, 0, stream>>>(W2ih, W2hh, w2s, 4096 * 1024);
    add_vec<<<2048, 256, 0, stream>>>(W3ih, W3hh, w3s, 4096 * 1024);
    add_vec<<<16, 256, 0, stream>>>(b1ih, b1hh, b1s, 4096);
    add_vec<<<16, 256, 0, stream>>>(b2ih, b2hh, b2s, 4096);
    add_vec<<<16, 256, 0, stream>>>(b3ih, b3hh, b3s, 4096);

    for (int step = 0; step < LL; ++step) {
        const float* inp   = (step == 0) ? decode_input : (out + (size_t)(step - 1) * HH);
        const float* hprev = (step == 0) ? h0 : h3;
        const float* cprev = (step == 0) ? c0 : c3;

        // attention logits: z = [inp | hprev] @ Wa.T   (N=512, K=2048, S=8)
        gemm_splitk<<<dim3(8, 8), 256, 0, stream>>>(inp, LH, 1024, hprev, 1024,
                                                    Wa, 2048, zp, 512, 256);
        // softmax + attn write + einsum -> applied
        softmax_einsum<<<dim3(64, 4), 256, 0, stream>>>(
            zp, ba, enc, applied, out + ATT0 + (size_t)step * MM, 8);

        // comb = relu([inp | applied] @ Wc.T + bc)   (N=1024, K=2048, S=8)
        gemm_splitk<<<dim3(16, 8), 256, 0, stream>>>(inp, LH, 1024, applied, 1024,
                                                     Wc, 2048, cpart, 1024, 256);
        reduce_act<<<256, 256, 0, stream>>>(cpart, 8, bc, comb, 1024);

        // LSTM1: gates = [comb | hprev] @ W1cat.T   (N=4096, K=2048, S=8)
        gemm_splitk<<<dim3(64, 8), 256, 0, stream>>>(comb, 1024, 1024, hprev, 1024,
                                                     w1cat, 2048, gp, 4096, 256);
        reduce_lstm<<<256, 256, 0, stream>>>(gp, 8, b1s, cprev, h1, c1);

        // LSTM2: gates = h1 @ (W2ih+W2hh).T   (N=4096, K=1024, S=4)
        gemm_splitk<<<dim3(64, 4), 256, 0, stream>>>(h1, 1024, 1024, nullptr, 0,
                                                     w2s, 1024, gp, 4096, 256);
        reduce_lstm<<<256, 256, 0, stream>>>(gp, 4, b2s, c1, h2, c2);

        // LSTM3
        gemm_splitk<<<dim3(64, 4), 256, 0, stream>>>(h2, 1024, 1024, nullptr, 0,
                                                     w3s, 1024, gp, 4096, 256);
        reduce_lstm<<<256, 256, 0, stream>>>(gp, 4, b3s, c2, h3, c3);

        // out = relu(h3 @ Wo.T + bo) -> d_out decode slot (also next step's input)
        gemm_splitk<<<dim3(16, 4), 256, 0, stream>>>(h3, 1024, 1024, nullptr, 0,
                                                     Wo, 1024, zp, 1024, 256);
        reduce_act<<<256, 256, 0, stream>>>(zp, 4, bo, out + (size_t)step * HH, LH);
    }
}